// Round 3
// baseline (1656.254 us; speedup 1.0000x reference)
//
#include <hip/hip_runtime.h>
#include <math.h>

#define N_NODES 100000
#define N_EDGES 1600000
#define F_IN    512
#define HID     128
#define NCLS    64
#define NLAYERS 8
#define NT      (N_NODES / 16)            // 6250 exact row-tiles of 16
#define NCHUNK  8
#define CHSZ    (N_NODES / NCHUNK)        // 12500 src nodes per chunk (3.2 MB of h)
#define N8      (N_NODES * NCHUNK)        // 800000 sub-rows
#define G8      (N8 / 256)                // 3125 exact
#define G8B     ((G8 + 255) / 256)        // 13

typedef __attribute__((ext_vector_type(8))) short short8;
typedef __attribute__((ext_vector_type(4))) float float4v;

// XOR swizzle for the A-fragment LDS region: brings the fragment-q bits (8..9)
// into bank bits (4..5). Involution; applied on both write and read.
#define SWZB(b) ((b) ^ ((((b) >> 8) & 3) << 4))

// ---- bf16 helpers (round-to-nearest-even) ----
__device__ inline unsigned short f2bf(float f) {
    unsigned int u = __float_as_uint(f);
    unsigned int r = u + 0x7fffu + ((u >> 16) & 1u);
    return (unsigned short)(r >> 16);
}
__device__ inline float bf2f(unsigned short h) {
    return __uint_as_float(((unsigned int)h) << 16);
}
__device__ inline uint4 pack8(const unsigned short* v) {
    uint4 u;
    u.x = (unsigned)v[0] | ((unsigned)v[1] << 16);
    u.y = (unsigned)v[2] | ((unsigned)v[3] << 16);
    u.z = (unsigned)v[4] | ((unsigned)v[5] << 16);
    u.w = (unsigned)v[6] | ((unsigned)v[7] << 16);
    return u;
}
// accumulate 8 bf16 (packed uint4, low/high order) * v into a[8]
__device__ inline void bf8_fma(float* a, uint4 u, float v) {
    a[0] += v * __uint_as_float(u.x << 16);
    a[1] += v * __uint_as_float(u.x & 0xffff0000u);
    a[2] += v * __uint_as_float(u.y << 16);
    a[3] += v * __uint_as_float(u.y & 0xffff0000u);
    a[4] += v * __uint_as_float(u.z << 16);
    a[5] += v * __uint_as_float(u.z & 0xffff0000u);
    a[6] += v * __uint_as_float(u.w << 16);
    a[7] += v * __uint_as_float(u.w & 0xffff0000u);
}
__device__ inline void unpack8(float* f, uint4 u) {
    f[0] = __uint_as_float(u.x << 16); f[1] = __uint_as_float(u.x & 0xffff0000u);
    f[2] = __uint_as_float(u.y << 16); f[3] = __uint_as_float(u.y & 0xffff0000u);
    f[4] = __uint_as_float(u.z << 16); f[5] = __uint_as_float(u.z & 0xffff0000u);
    f[6] = __uint_as_float(u.w << 16); f[7] = __uint_as_float(u.w & 0xffff0000u);
}
// split fp32 into hi/lo bf16 and store into vector element j of ahi/alo
__device__ inline void split_into(short8& ahi, short8& alo, int j, float f) {
    unsigned short h = f2bf(f);
    ahi[j] = (short)h;
    alo[j] = (short)f2bf(f - bf2f(h));
}

// ================= chunked CSR build =================
// ptr16[node*8+c] = start of edges with dst=node whose src lies in chunk c.
// rec ordered (dst-major, chunk-minor, arbitrary within).

__global__ __launch_bounds__(256) void zero16(int* __restrict__ cnt16) {
    int i = blockIdx.x * 256 + threadIdx.x;
    if (i < N8) cnt16[i] = 0;
}
__global__ __launch_bounds__(256) void cnt16_count(const int* __restrict__ srcI,
                                                   const int* __restrict__ dstI,
                                                   int* __restrict__ cnt16) {
    int e = blockIdx.x * 256 + threadIdx.x;
    if (e < N_EDGES) {
        int s = srcI[e], d = dstI[e];
        atomicAdd(&cnt16[d * NCHUNK + s / CHSZ], 1);
    }
}
// generic inclusive per-256-block scan; part = inclusive, bsum = block totals
__global__ __launch_bounds__(256) void scan_incl(const int* __restrict__ in, int n,
                                                 int* __restrict__ part,
                                                 int* __restrict__ bsum) {
    __shared__ int tmp[256];
    int t = threadIdx.x, i = blockIdx.x * 256 + t;
    int v = (i < n) ? in[i] : 0;
    tmp[t] = v;
    __syncthreads();
#pragma unroll
    for (int off = 1; off < 256; off <<= 1) {
        int add = (t >= off) ? tmp[t - off] : 0;
        __syncthreads();
        tmp[t] += add;
        __syncthreads();
    }
    if (i < n) part[i] = tmp[t];
    if (t == 255) bsum[blockIdx.x] = tmp[255];
}
__global__ void scan_ser(int* __restrict__ b, int n) {
    if (threadIdx.x == 0 && blockIdx.x == 0) {
        int acc = 0;
        for (int i = 0; i < n; i++) { int v = b[i]; b[i] = acc; acc += v; }
    }
}
__global__ __launch_bounds__(256) void finalize16(const int* __restrict__ cnt16,
        const int* __restrict__ part1, const int* __restrict__ part2,
        const int* __restrict__ b1, const int* __restrict__ b2,
        int* __restrict__ ptr16, int* __restrict__ cursor16) {
    int i = blockIdx.x * 256 + threadIdx.x;
    if (i < N8) {
        int j = i >> 8;
        int ex = part1[i] - cnt16[i] + (part2[j] - b1[j]) + b2[j >> 8];
        ptr16[i] = ex;
        cursor16[i] = ex;
        if (i == N8 - 1) ptr16[N8] = ex + cnt16[i];
    }
}
__global__ __launch_bounds__(256) void make_dinv16(const int* __restrict__ ptr16,
                                                   float* __restrict__ dinv) {
    int i = blockIdx.x * 256 + threadIdx.x;
    if (i < N_NODES) {
        int deg = ptr16[i * NCHUNK + NCHUNK] - ptr16[i * NCHUNK];
        dinv[i] = rsqrtf((float)(deg + 1));
    }
}
__global__ __launch_bounds__(256) void scatter16(const int* __restrict__ srcI,
                                                 const int* __restrict__ dstI,
                                                 const float* __restrict__ dinv,
                                                 int* __restrict__ cursor16,
                                                 int2* __restrict__ rec) {
    int e = blockIdx.x * 256 + threadIdx.x;
    if (e < N_EDGES) {
        int s = srcI[e], d = dstI[e];
        int pos = atomicAdd(&cursor16[d * NCHUNK + s / CHSZ], 1);
        rec[pos] = make_int2(s, __float_as_int(dinv[s] * dinv[d]));
    }
}

// ================= weight pre-conversion =================
// Layout: chunk-major. wip chunk c (c=0..15) = 16 KB contiguous: 8 nt-frags of
// 1024 ushorts each (hi at [0,512), lo at [512,1024)), frag elem = lane*8+j.
__global__ __launch_bounds__(64) void conv_win(const float* __restrict__ w,
                                               unsigned short* __restrict__ wip) {
    int nt = blockIdx.x >> 4;
    int c  = blockIdx.x & 15;
    int lane = threadIdx.x;
    int n  = nt * 16 + (lane & 15);
    int kb = c * 32 + (lane >> 4) * 8;
    unsigned short hi[8], lo[8];
#pragma unroll
    for (int j = 0; j < 8; j++) {
        float v = w[(size_t)(kb + j) * HID + n];
        hi[j] = f2bf(v);
        lo[j] = f2bf(v - bf2f(hi[j]));
    }
    size_t base = ((size_t)c * 8 + nt) * 1024 + (size_t)lane * 8;
    *(uint4*)&wip[base]       = pack8(hi);
    *(uint4*)&wip[base + 512] = pack8(lo);
}

// W'_l = beta_l * conv_w[l] + (1-beta_l) * I ; chunk-major per layer (c=0..3)
__global__ __launch_bounds__(64) void conv_wl(const float* __restrict__ cw,
                                              unsigned short* __restrict__ wlp) {
    int l  = blockIdx.x >> 5;
    int nt = (blockIdx.x >> 2) & 7;
    int c  = blockIdx.x & 3;
    int lane = threadIdx.x;
    float beta = logf(0.5f / (float)(l + 1) + 1.0f);
    int n  = nt * 16 + (lane & 15);
    int kb = c * 32 + (lane >> 4) * 8;
    const float* W = cw + (size_t)l * HID * HID;
    unsigned short hi[8], lo[8];
#pragma unroll
    for (int j = 0; j < 8; j++) {
        int k = kb + j;
        float v = beta * W[(size_t)k * HID + n] + ((k == n) ? (1.0f - beta) : 0.0f);
        hi[j] = f2bf(v);
        lo[j] = f2bf(v - bf2f(hi[j]));
    }
    size_t base = (size_t)l * 32768 + ((size_t)c * 8 + nt) * 1024 + (size_t)lane * 8;
    *(uint4*)&wlp[base]       = pack8(hi);
    *(uint4*)&wlp[base + 512] = pack8(lo);
}

// w_out [128][64] -> B-frags hi/lo per (nt 0..3, c 0..3) (local layout, unstaged)
__global__ __launch_bounds__(64) void conv_wout(const float* __restrict__ w,
                                                unsigned short* __restrict__ wop) {
    int nt = blockIdx.x >> 2;
    int c  = blockIdx.x & 3;
    int lane = threadIdx.x;
    int n  = nt * 16 + (lane & 15);
    int kb = c * 32 + (lane >> 4) * 8;
    unsigned short hi[8], lo[8];
#pragma unroll
    for (int j = 0; j < 8; j++) {
        float v = w[(size_t)(kb + j) * NCLS + n];
        hi[j] = f2bf(v);
        lo[j] = f2bf(v - bf2f(hi[j]));
    }
    size_t base = ((size_t)nt * 4 + c) * 1024 + (size_t)lane * 8;
    *(uint4*)&wop[base]       = pack8(hi);
    *(uint4*)&wop[base + 512] = pack8(lo);
}

// ================= input GEMM: h = x @ w_in + b (LDS-staged weights) =================
__global__ __launch_bounds__(256) void in_gemm_mfma(const float* __restrict__ x,
        const unsigned short* __restrict__ wip, const float* __restrict__ bias,
        unsigned short* __restrict__ hb, unsigned short* __restrict__ h0b) {
    __shared__ unsigned short wlds[8192];      // 16 KB: one K-chunk of B-frags
    __shared__ unsigned short tile[64][136];   // 17 KB output staging
    int tid = threadIdx.x;
    int wave = tid >> 6, lane = tid & 63;
    int t = blockIdx.x * 4 + wave;
    int m = lane & 15, q = lane >> 4;
    int tc = (t < NT) ? t : (NT - 1);          // clamp for address safety

    const uint4* wg = (const uint4*)wip;       // chunk c at uint4 index c*1024
    uint4 pf0 = wg[tid];
    uint4 pf1 = wg[tid + 256];
    uint4 pf2 = wg[tid + 512];
    uint4 pf3 = wg[tid + 768];

    float4v acc[8];
#pragma unroll
    for (int nt = 0; nt < 8; nt++) acc[nt] = (float4v){0.f, 0.f, 0.f, 0.f};
    const float* xr = x + (size_t)(tc * 16 + m) * F_IN + q * 8;
    uint4* wl4 = (uint4*)wlds;

    for (int c = 0; c < 16; c++) {
        wl4[tid] = pf0; wl4[tid + 256] = pf1; wl4[tid + 512] = pf2; wl4[tid + 768] = pf3;
        __syncthreads();
        if (c < 15) {
            const uint4* wn = wg + (size_t)(c + 1) * 1024;
            pf0 = wn[tid]; pf1 = wn[tid + 256]; pf2 = wn[tid + 512]; pf3 = wn[tid + 768];
        }
        float4 x0 = *(const float4*)(xr + c * 32);
        float4 x1 = *(const float4*)(xr + c * 32 + 4);
        short8 ahi, alo;
        split_into(ahi, alo, 0, x0.x); split_into(ahi, alo, 1, x0.y);
        split_into(ahi, alo, 2, x0.z); split_into(ahi, alo, 3, x0.w);
        split_into(ahi, alo, 4, x1.x); split_into(ahi, alo, 5, x1.y);
        split_into(ahi, alo, 6, x1.z); split_into(ahi, alo, 7, x1.w);
#pragma unroll
        for (int nt = 0; nt < 8; nt++) {
            short8 bhi = *(short8*)&wlds[nt * 1024 + lane * 8];
            short8 blo = *(short8*)&wlds[nt * 1024 + 512 + lane * 8];
            acc[nt] = __builtin_amdgcn_mfma_f32_16x16x32_bf16(ahi, bhi, acc[nt], 0, 0, 0);
            acc[nt] = __builtin_amdgcn_mfma_f32_16x16x32_bf16(ahi, blo, acc[nt], 0, 0, 0);
            acc[nt] = __builtin_amdgcn_mfma_f32_16x16x32_bf16(alo, bhi, acc[nt], 0, 0, 0);
        }
        __syncthreads();
    }

    if (t < NT) {
#pragma unroll
        for (int nt = 0; nt < 8; nt++) {
            float bb = bias[nt * 16 + m];
#pragma unroll
            for (int r = 0; r < 4; r++)
                tile[wave * 16 + q * 4 + r][nt * 16 + m] = f2bf(acc[nt][r] + bb);
        }
    }
    __syncthreads();

    int nl = tid >> 2, part = tid & 3;
    int node = blockIdx.x * 64 + nl;
    if (node < N_NODES) {
        uint4* d1 = (uint4*)&hb [(size_t)node * HID + part * 32];
        uint4* d2 = (uint4*)&h0b[(size_t)node * HID + part * 32];
#pragma unroll
        for (int j = 0; j < 4; j++) {
            uint4 u = *(uint4*)&tile[nl][part * 32 + j * 8];
            d1[j] = u; d2[j] = u;
        }
    }
}

// ================= fused SpMM + residual mix + layer GEMM =================
// Block = 64 nodes (4 waves). Phase 1: one node per 16-lane quarter; edges
// consumed CHUNK-BY-CHUNK (src chunk = 3.2 MB of h, L2-resident since all
// blocks sweep chunks in the same order). Aggregate in registers, residual-mix,
// write MFMA A-frags into swizzled LDS. Phase 2: GEMM h_out = elu(s @ W'_l).
template <int LAST>
__global__ __launch_bounds__(256, 4) void spmm_gemm(const int* __restrict__ ptr16,
        const int2* __restrict__ rec, const float* __restrict__ dinv,
        const unsigned short* __restrict__ hin, const unsigned short* __restrict__ h0b,
        const unsigned short* __restrict__ wlp, void* __restrict__ outp) {
    __shared__ __align__(16) unsigned short afr[16384];   // 32 KB A-frags / out-tile union
    int tid = threadIdx.x;
    int wave = tid >> 6, lane = tid & 63;
    int qu = lane >> 4, fl = lane & 15;
    char* af = (char*)afr;

    // ---- phase 1: aggregation, 4 rounds of (node per quarter), chunk-ordered ----
    int base = blockIdx.x * 64 + wave * 16;
#pragma unroll 1
    for (int g = 0; g < 4; ++g) {
        int node = base + g * 4 + qu;
        int nc = (node < N_NODES) ? node : (N_NODES - 1);
        // lane fl (<=8) holds ptr16[nc*8+fl]; chunk bounds fetched via shfl
        int pv = ptr16[nc * NCHUNK + ((fl < 9) ? fl : 8)];
        // issue self/residual loads early (overlap with gather)
        float dd = dinv[nc];
        uint4 hv = *(const uint4*)(hin + (size_t)nc * HID + fl * 8);
        uint4 zv = *(const uint4*)(h0b + (size_t)nc * HID + fl * 8);
        float a[8] = {0.f, 0.f, 0.f, 0.f, 0.f, 0.f, 0.f, 0.f};
        for (int c = 0; c < NCHUNK; ++c) {
            int e0 = __shfl(pv, (qu << 4) + c);
            int e1 = __shfl(pv, (qu << 4) + c + 1);
            int e = e0;
            for (; e + 1 < e1; e += 2) {
                int2 r0 = rec[e], r1 = rec[e + 1];
                uint4 u0 = *(const uint4*)(hin + (size_t)r0.x * HID + fl * 8);
                uint4 u1 = *(const uint4*)(hin + (size_t)r1.x * HID + fl * 8);
                bf8_fma(a, u0, __int_as_float(r0.y));
                bf8_fma(a, u1, __int_as_float(r1.y));
            }
            if (e < e1) {
                int2 r0 = rec[e];
                uint4 u0 = *(const uint4*)(hin + (size_t)r0.x * HID + fl * 8);
                bf8_fma(a, u0, __int_as_float(r0.y));
            }
        }
        // self-loop + initial-residual mix
        float d2 = dd * dd;
        float hvf[8], zvf[8];
        unpack8(hvf, hv);
        unpack8(zvf, zv);
        short8 ohi, olo;
#pragma unroll
        for (int j = 0; j < 8; ++j) {
            float o = 0.9f * (a[j] + d2 * hvf[j]) + 0.1f * zvf[j];
            split_into(ohi, olo, j, o);
        }
        // A-frag layout: byte = wave*8192 + c*2048 + sel*1024 + q*256 + m*16
        int mrow = g * 4 + qu;
        int b0 = wave * 8192 + (fl >> 2) * 2048 + (fl & 3) * 256 + mrow * 16;
        *(short8*)(af + SWZB(b0)) = ohi;
        *(short8*)(af + SWZB(b0 + 1024)) = olo;
    }
    __syncthreads();   // all A-frags visible

    // ---- phase 2: GEMM, A from LDS, B from global ----
    float4v acc[8];
#pragma unroll
    for (int nt = 0; nt < 8; ++nt) acc[nt] = (float4v){0.f, 0.f, 0.f, 0.f};
    const short8* wp8 = (const short8*)wlp;
#pragma unroll
    for (int c = 0; c < 4; ++c) {
        int rb = wave * 8192 + c * 2048 + lane * 16;
        short8 ahi = *(const short8*)(af + SWZB(rb));
        short8 alo = *(const short8*)(af + SWZB(rb + 1024));
#pragma unroll
        for (int nt = 0; nt < 8; ++nt) {
            short8 bhi = wp8[(size_t)(c * 8 + nt) * 128 + lane];
            short8 blo = wp8[(size_t)(c * 8 + nt) * 128 + 64 + lane];
            acc[nt] = __builtin_amdgcn_mfma_f32_16x16x32_bf16(ahi, bhi, acc[nt], 0, 0, 0);
            acc[nt] = __builtin_amdgcn_mfma_f32_16x16x32_bf16(ahi, blo, acc[nt], 0, 0, 0);
            acc[nt] = __builtin_amdgcn_mfma_f32_16x16x32_bf16(alo, bhi, acc[nt], 0, 0, 0);
        }
    }

    if (LAST) {
        // write f32 h for the out GEMM
        int t = blockIdx.x * 4 + wave;
        if (t < NT) {
            float* hf = (float*)outp;
#pragma unroll
            for (int nt = 0; nt < 8; ++nt) {
#pragma unroll
                for (int r = 0; r < 4; ++r) {
                    float v = acc[nt][r];
                    v = (v > 0.f) ? v : (expf(v) - 1.0f);
                    hf[(size_t)(t * 16 + qu * 4 + r) * HID + nt * 16 + fl] = v;
                }
            }
        }
    } else {
        __syncthreads();   // A-frag reads done; reuse afr as output tile
        unsigned short (*tile)[136] = (unsigned short (*)[136])afr;
#pragma unroll
        for (int nt = 0; nt < 8; ++nt) {
#pragma unroll
            for (int r = 0; r < 4; ++r) {
                float v = acc[nt][r];
                v = (v > 0.f) ? v : (expf(v) - 1.0f);
                tile[wave * 16 + qu * 4 + r][nt * 16 + fl] = f2bf(v);
            }
        }
        __syncthreads();
        unsigned short* hout = (unsigned short*)outp;
        int nl = tid >> 2, part = tid & 3;
        int node = blockIdx.x * 64 + nl;
        if (node < N_NODES) {
            uint4* d1 = (uint4*)&hout[(size_t)node * HID + part * 32];
#pragma unroll
            for (int j = 0; j < 4; ++j) d1[j] = *(uint4*)&tile[nl][part * 32 + j * 8];
        }
    }
}

// ================= out GEMM + log_softmax (split-bf16 MFMA) =================
__global__ __launch_bounds__(256) void out_gemm(const float* __restrict__ hf,
        const unsigned short* __restrict__ wop, const float* __restrict__ bias,
        float* __restrict__ out) {
    int wave = threadIdx.x >> 6;
    int lane = threadIdx.x & 63;
    int t = blockIdx.x * 4 + wave;
    int m = lane & 15, q = lane >> 4;
    if (t >= NT) return;

    float4v acc[4];
#pragma unroll
    for (int nt = 0; nt < 4; nt++) acc[nt] = (float4v){0.f, 0.f, 0.f, 0.f};
    const float* hr = hf + (size_t)(t * 16 + m) * HID + q * 8;
    const short8* wp8 = (const short8*)wop;
#pragma unroll
    for (int c = 0; c < 4; c++) {
        float4 x0 = *(const float4*)(hr + c * 32);
        float4 x1 = *(const float4*)(hr + c * 32 + 4);
        short8 ahi, alo;
        split_into(ahi, alo, 0, x0.x); split_into(ahi, alo, 1, x0.y);
        split_into(ahi, alo, 2, x0.z); split_into(ahi, alo, 3, x0.w);
        split_into(ahi, alo, 4, x1.x); split_into(ahi, alo, 5, x1.y);
        split_into(ahi, alo, 6, x1.z); split_into(ahi, alo, 7, x1.w);
#pragma unroll
        for (int nt = 0; nt < 4; nt++) {
            short8 bhi = wp8[(size_t)(nt * 4 + c) * 128 + lane];
            short8 blo = wp8[(size_t)(nt * 4 + c) * 128 + 64 + lane];
            acc[nt] = __builtin_amdgcn_mfma_f32_16x16x32_bf16(ahi, bhi, acc[nt], 0, 0, 0);
            acc[nt] = __builtin_amdgcn_mfma_f32_16x16x32_bf16(ahi, blo, acc[nt], 0, 0, 0);
            acc[nt] = __builtin_amdgcn_mfma_f32_16x16x32_bf16(alo, bhi, acc[nt], 0, 0, 0);
        }
    }
    float bn[4];
#pragma unroll
    for (int nt = 0; nt < 4; nt++) bn[nt] = bias[nt * 16 + m];
#pragma unroll
    for (int r = 0; r < 4; r++) {
        float v0 = acc[0][r] + bn[0], v1 = acc[1][r] + bn[1];
        float v2 = acc[2][r] + bn[2], v3 = acc[3][r] + bn[3];
        float mx = fmaxf(fmaxf(v0, v1), fmaxf(v2, v3));
#pragma unroll
        for (int msk = 1; msk < 16; msk <<= 1) mx = fmaxf(mx, __shfl_xor(mx, msk));
        float ssum = expf(v0 - mx) + expf(v1 - mx) + expf(v2 - mx) + expf(v3 - mx);
#pragma unroll
        for (int msk = 1; msk < 16; msk <<= 1) ssum += __shfl_xor(ssum, msk);
        float lg = mx + logf(ssum);
        size_t base = (size_t)(t * 16 + q * 4 + r) * NCLS + m;
        out[base]      = v0 - lg;
        out[base + 16] = v1 - lg;
        out[base + 32] = v2 - lg;
        out[base + 48] = v3 - lg;
    }
}

// ================= launch =================

extern "C" void kernel_launch(void* const* d_in, const int* in_sizes, int n_in,
                              void* d_out, int out_size, void* d_ws, size_t ws_size,
                              hipStream_t stream) {
    const float* x      = (const float*)d_in[0];
    const int*   ei     = (const int*)  d_in[1];
    const float* w_in   = (const float*)d_in[2];
    const float* b_in   = (const float*)d_in[3];
    const float* conv_w = (const float*)d_in[4];
    const float* w_out  = (const float*)d_in[5];
    const float* b_out  = (const float*)d_in[6];
    float* out = (float*)d_out;

    const int* srcI = ei;
    const int* dstI = ei + N_EDGES;

    char* ws = (char*)d_ws;
    float* dinv    = (float*)(ws + 0x000000);                  // 400 KB
    int2*  rec     = (int2*) (ws + 0x280000);                  // 12.8 MB
    unsigned short* wip = (unsigned short*)(ws + 0xF00000);    // 256 KB
    unsigned short* wlp = (unsigned short*)(ws + 0xF40000);    // 512 KB
    unsigned short* wop = (unsigned short*)(ws + 0xFC0000);    // 32 KB
    unsigned short* hb  = (unsigned short*)(ws + 0x1000000);   // 25.6 MB
    unsigned short* h0b = hb + (size_t)N_NODES * HID;          // 25.6 MB
    unsigned short* hb2 = h0b + (size_t)N_NODES * HID;         // 25.6 MB (ping-pong)
    float* hf = (float*)(hb2 + 2 * (size_t)N_NODES * HID);     // 51.2 MB
    int* ptr16    = (int*)(hf + (size_t)N_NODES * HID);        // 3.2 MB + 4
    int* cursor16 = ptr16 + (N8 + 64);                         // 3.2 MB
    int* cnt16    = cursor16 + N8;                             // 3.2 MB
    int* part1    = cnt16 + N8;                                // 3.2 MB
    int* b1       = part1 + N8;                                // 16 KB
    int* part2    = b1 + 4096;                                 // 16 KB
    int* b2       = part2 + 4096;                              // small

    int gN = (N_NODES + 255) / 256;
    int gE = (N_EDGES + 255) / 256;
    int gT = (NT + 3) / 4;                                     // 1563 (= 64-node blocks)

    zero16<<<G8, 256, 0, stream>>>(cnt16);
    cnt16_count<<<gE, 256, 0, stream>>>(srcI, dstI, cnt16);
    scan_incl<<<G8, 256, 0, stream>>>(cnt16, N8, part1, b1);
    scan_incl<<<G8B, 256, 0, stream>>>(b1, G8, part2, b2);
    scan_ser<<<1, 64, 0, stream>>>(b2, G8B);
    finalize16<<<G8, 256, 0, stream>>>(cnt16, part1, part2, b1, b2, ptr16, cursor16);
    make_dinv16<<<gN, 256, 0, stream>>>(ptr16, dinv);
    scatter16<<<gE, 256, 0, stream>>>(srcI, dstI, dinv, cursor16, rec);

    conv_win<<<128, 64, 0, stream>>>(w_in, wip);
    conv_wl<<<256, 64, 0, stream>>>(conv_w, wlp);
    conv_wout<<<16, 64, 0, stream>>>(w_out, wop);

    in_gemm_mfma<<<gT, 256, 0, stream>>>(x, wip, b_in, hb, h0b);

    unsigned short* cur = hb;
    unsigned short* nxt = hb2;
    for (int l = 0; l < NLAYERS; l++) {
        const unsigned short* wl = wlp + (size_t)l * 32768;
        if (l < NLAYERS - 1) {
            spmm_gemm<0><<<gT, 256, 0, stream>>>(ptr16, rec, dinv, cur, h0b, wl, nxt);
            unsigned short* t = cur; cur = nxt; nxt = t;
        } else {
            spmm_gemm<1><<<gT, 256, 0, stream>>>(ptr16, rec, dinv, cur, h0b, wl, hf);
        }
    }

    out_gemm<<<gT, 256, 0, stream>>>(hf, wop, b_out, out);
}

// Round 4
// 1208.490 us; speedup vs baseline: 1.3705x; 1.3705x over previous
//
#include <hip/hip_runtime.h>
#include <math.h>

#define N_NODES 100000
#define N_EDGES 1600000
#define F_IN    512
#define HID     128
#define NCLS    64
#define NLAYERS 8
#define NT      (N_NODES / 16)            // 6250 exact row-tiles of 16
#define NSCANB  ((N_NODES + 255) / 256)   // 391

typedef __attribute__((ext_vector_type(8))) short short8;
typedef __attribute__((ext_vector_type(4))) float float4v;

// XOR swizzle for the A-fragment LDS region: brings the fragment-q bits (8..9)
// into bank bits (4..5). Involution; applied on both write and read.
#define SWZB(b) ((b) ^ ((((b) >> 8) & 3) << 4))

// ---- bf16 helpers (round-to-nearest-even) ----
__device__ inline unsigned short f2bf(float f) {
    unsigned int u = __float_as_uint(f);
    unsigned int r = u + 0x7fffu + ((u >> 16) & 1u);
    return (unsigned short)(r >> 16);
}
__device__ inline float bf2f(unsigned short h) {
    return __uint_as_float(((unsigned int)h) << 16);
}
__device__ inline uint4 pack8(const unsigned short* v) {
    uint4 u;
    u.x = (unsigned)v[0] | ((unsigned)v[1] << 16);
    u.y = (unsigned)v[2] | ((unsigned)v[3] << 16);
    u.z = (unsigned)v[4] | ((unsigned)v[5] << 16);
    u.w = (unsigned)v[6] | ((unsigned)v[7] << 16);
    return u;
}
// accumulate 8 bf16 (packed uint4, low/high order) * v into a[8]
__device__ inline void bf8_fma(float* a, uint4 u, float v) {
    a[0] += v * __uint_as_float(u.x << 16);
    a[1] += v * __uint_as_float(u.x & 0xffff0000u);
    a[2] += v * __uint_as_float(u.y << 16);
    a[3] += v * __uint_as_float(u.y & 0xffff0000u);
    a[4] += v * __uint_as_float(u.z << 16);
    a[5] += v * __uint_as_float(u.z & 0xffff0000u);
    a[6] += v * __uint_as_float(u.w << 16);
    a[7] += v * __uint_as_float(u.w & 0xffff0000u);
}
__device__ inline void unpack8(float* f, uint4 u) {
    f[0] = __uint_as_float(u.x << 16); f[1] = __uint_as_float(u.x & 0xffff0000u);
    f[2] = __uint_as_float(u.y << 16); f[3] = __uint_as_float(u.y & 0xffff0000u);
    f[4] = __uint_as_float(u.z << 16); f[5] = __uint_as_float(u.z & 0xffff0000u);
    f[6] = __uint_as_float(u.w << 16); f[7] = __uint_as_float(u.w & 0xffff0000u);
}
// split fp32 into hi/lo bf16 and store into vector element j of ahi/alo
__device__ inline void split_into(short8& ahi, short8& alo, int j, float f) {
    unsigned short h = f2bf(f);
    ahi[j] = (short)h;
    alo[j] = (short)f2bf(f - bf2f(h));
}

// ================= CSR build =================

__global__ __launch_bounds__(256) void cnt_init(int* __restrict__ cnt) {
    int i = blockIdx.x * 256 + threadIdx.x;
    if (i < N_NODES) cnt[i] = 0;
}
__global__ __launch_bounds__(256) void cnt_count(const int* __restrict__ dst,
                                                 int* __restrict__ cnt) {
    int e = blockIdx.x * 256 + threadIdx.x;
    if (e < N_EDGES) atomicAdd(&cnt[dst[e]], 1);
}
__global__ __launch_bounds__(256) void make_dinv(const int* __restrict__ cnt,
                                                 float* __restrict__ dinv) {
    int i = blockIdx.x * 256 + threadIdx.x;
    if (i < N_NODES) dinv[i] = rsqrtf((float)(cnt[i] + 1));
}
__global__ __launch_bounds__(256) void scan_block(const int* __restrict__ cnt,
                                                  int* __restrict__ partial,
                                                  int* __restrict__ bsum) {
    __shared__ int tmp[256];
    int t = threadIdx.x, i = blockIdx.x * 256 + t;
    int v = (i < N_NODES) ? cnt[i] : 0;
    tmp[t] = v;
    __syncthreads();
#pragma unroll
    for (int off = 1; off < 256; off <<= 1) {
        int add = (t >= off) ? tmp[t - off] : 0;
        __syncthreads();
        tmp[t] += add;
        __syncthreads();
    }
    if (i < N_NODES) partial[i] = tmp[t];
    if (t == 255) bsum[blockIdx.x] = tmp[255];
}
__global__ void scan_bsum(int* __restrict__ bsum) {
    if (threadIdx.x == 0 && blockIdx.x == 0) {
        int acc = 0;
        for (int i = 0; i < NSCANB; i++) { int v = bsum[i]; bsum[i] = acc; acc += v; }
    }
}
__global__ __launch_bounds__(256) void finalize_rowptr(const int* __restrict__ cnt,
                                                       const int* __restrict__ partial,
                                                       const int* __restrict__ bsum,
                                                       int* __restrict__ row_ptr,
                                                       int* __restrict__ cursor) {
    int i = blockIdx.x * 256 + threadIdx.x;
    if (i < N_NODES) {
        int ex = partial[i] - cnt[i] + bsum[blockIdx.x];
        row_ptr[i] = ex;
        cursor[i]  = ex;
        if (i == N_NODES - 1) row_ptr[N_NODES] = ex + cnt[i];
    }
}
__global__ __launch_bounds__(256) void scatter_edges(const int* __restrict__ srcI,
                                                     const int* __restrict__ dstI,
                                                     const float* __restrict__ dinv,
                                                     int* __restrict__ cursor,
                                                     int2* __restrict__ rec) {
    int e = blockIdx.x * 256 + threadIdx.x;
    if (e < N_EDGES) {
        int s = srcI[e], d = dstI[e];
        int pos = atomicAdd(&cursor[d], 1);
        rec[pos] = make_int2(s, __float_as_int(dinv[s] * dinv[d]));
    }
}

// ================= weight pre-conversion =================
// Layout: chunk-major. wip chunk c (c=0..15) = 16 KB contiguous: 8 nt-frags of
// 1024 ushorts each (hi at [0,512), lo at [512,1024)), frag elem = lane*8+j.
__global__ __launch_bounds__(64) void conv_win(const float* __restrict__ w,
                                               unsigned short* __restrict__ wip) {
    int nt = blockIdx.x >> 4;
    int c  = blockIdx.x & 15;
    int lane = threadIdx.x;
    int n  = nt * 16 + (lane & 15);
    int kb = c * 32 + (lane >> 4) * 8;
    unsigned short hi[8], lo[8];
#pragma unroll
    for (int j = 0; j < 8; j++) {
        float v = w[(size_t)(kb + j) * HID + n];
        hi[j] = f2bf(v);
        lo[j] = f2bf(v - bf2f(hi[j]));
    }
    size_t base = ((size_t)c * 8 + nt) * 1024 + (size_t)lane * 8;
    *(uint4*)&wip[base]       = pack8(hi);
    *(uint4*)&wip[base + 512] = pack8(lo);
}

// W'_l = beta_l * conv_w[l] + (1-beta_l) * I ; chunk-major per layer (c=0..3)
__global__ __launch_bounds__(64) void conv_wl(const float* __restrict__ cw,
                                              unsigned short* __restrict__ wlp) {
    int l  = blockIdx.x >> 5;
    int nt = (blockIdx.x >> 2) & 7;
    int c  = blockIdx.x & 3;
    int lane = threadIdx.x;
    float beta = logf(0.5f / (float)(l + 1) + 1.0f);
    int n  = nt * 16 + (lane & 15);
    int kb = c * 32 + (lane >> 4) * 8;
    const float* W = cw + (size_t)l * HID * HID;
    unsigned short hi[8], lo[8];
#pragma unroll
    for (int j = 0; j < 8; j++) {
        int k = kb + j;
        float v = beta * W[(size_t)k * HID + n] + ((k == n) ? (1.0f - beta) : 0.0f);
        hi[j] = f2bf(v);
        lo[j] = f2bf(v - bf2f(hi[j]));
    }
    size_t base = (size_t)l * 32768 + ((size_t)c * 8 + nt) * 1024 + (size_t)lane * 8;
    *(uint4*)&wlp[base]       = pack8(hi);
    *(uint4*)&wlp[base + 512] = pack8(lo);
}

// w_out [128][64] -> B-frags hi/lo per (nt 0..3, c 0..3) (local layout, unstaged)
__global__ __launch_bounds__(64) void conv_wout(const float* __restrict__ w,
                                                unsigned short* __restrict__ wop) {
    int nt = blockIdx.x >> 2;
    int c  = blockIdx.x & 3;
    int lane = threadIdx.x;
    int n  = nt * 16 + (lane & 15);
    int kb = c * 32 + (lane >> 4) * 8;
    unsigned short hi[8], lo[8];
#pragma unroll
    for (int j = 0; j < 8; j++) {
        float v = w[(size_t)(kb + j) * NCLS + n];
        hi[j] = f2bf(v);
        lo[j] = f2bf(v - bf2f(hi[j]));
    }
    size_t base = ((size_t)nt * 4 + c) * 1024 + (size_t)lane * 8;
    *(uint4*)&wop[base]       = pack8(hi);
    *(uint4*)&wop[base + 512] = pack8(lo);
}

// ================= input GEMM: h = x @ w_in + b (LDS-staged weights) =================
__global__ __launch_bounds__(256) void in_gemm_mfma(const float* __restrict__ x,
        const unsigned short* __restrict__ wip, const float* __restrict__ bias,
        unsigned short* __restrict__ hb, unsigned short* __restrict__ h0b) {
    __shared__ unsigned short wlds[8192];      // 16 KB: one K-chunk of B-frags
    __shared__ unsigned short tile[64][136];   // 17 KB output staging
    int tid = threadIdx.x;
    int wave = tid >> 6, lane = tid & 63;
    int t = blockIdx.x * 4 + wave;
    int m = lane & 15, q = lane >> 4;
    int tc = (t < NT) ? t : (NT - 1);          // clamp for address safety

    const uint4* wg = (const uint4*)wip;       // chunk c at uint4 index c*1024
    uint4 pf0 = wg[tid];
    uint4 pf1 = wg[tid + 256];
    uint4 pf2 = wg[tid + 512];
    uint4 pf3 = wg[tid + 768];

    float4v acc[8];
#pragma unroll
    for (int nt = 0; nt < 8; nt++) acc[nt] = (float4v){0.f, 0.f, 0.f, 0.f};
    const float* xr = x + (size_t)(tc * 16 + m) * F_IN + q * 8;
    uint4* wl4 = (uint4*)wlds;

    for (int c = 0; c < 16; c++) {
        wl4[tid] = pf0; wl4[tid + 256] = pf1; wl4[tid + 512] = pf2; wl4[tid + 768] = pf3;
        __syncthreads();
        if (c < 15) {
            const uint4* wn = wg + (size_t)(c + 1) * 1024;
            pf0 = wn[tid]; pf1 = wn[tid + 256]; pf2 = wn[tid + 512]; pf3 = wn[tid + 768];
        }
        float4 x0 = *(const float4*)(xr + c * 32);
        float4 x1 = *(const float4*)(xr + c * 32 + 4);
        short8 ahi, alo;
        split_into(ahi, alo, 0, x0.x); split_into(ahi, alo, 1, x0.y);
        split_into(ahi, alo, 2, x0.z); split_into(ahi, alo, 3, x0.w);
        split_into(ahi, alo, 4, x1.x); split_into(ahi, alo, 5, x1.y);
        split_into(ahi, alo, 6, x1.z); split_into(ahi, alo, 7, x1.w);
#pragma unroll
        for (int nt = 0; nt < 8; nt++) {
            short8 bhi = *(short8*)&wlds[nt * 1024 + lane * 8];
            short8 blo = *(short8*)&wlds[nt * 1024 + 512 + lane * 8];
            acc[nt] = __builtin_amdgcn_mfma_f32_16x16x32_bf16(ahi, bhi, acc[nt], 0, 0, 0);
            acc[nt] = __builtin_amdgcn_mfma_f32_16x16x32_bf16(ahi, blo, acc[nt], 0, 0, 0);
            acc[nt] = __builtin_amdgcn_mfma_f32_16x16x32_bf16(alo, bhi, acc[nt], 0, 0, 0);
        }
        __syncthreads();
    }

    if (t < NT) {
#pragma unroll
        for (int nt = 0; nt < 8; nt++) {
            float bb = bias[nt * 16 + m];
#pragma unroll
            for (int r = 0; r < 4; r++)
                tile[wave * 16 + q * 4 + r][nt * 16 + m] = f2bf(acc[nt][r] + bb);
        }
    }
    __syncthreads();

    int nl = tid >> 2, part = tid & 3;
    int node = blockIdx.x * 64 + nl;
    if (node < N_NODES) {
        uint4* d1 = (uint4*)&hb [(size_t)node * HID + part * 32];
        uint4* d2 = (uint4*)&h0b[(size_t)node * HID + part * 32];
#pragma unroll
        for (int j = 0; j < 4; j++) {
            uint4 u = *(uint4*)&tile[nl][part * 32 + j * 8];
            d1[j] = u; d2[j] = u;
        }
    }
}

// ================= fused SpMM + residual mix + layer GEMM =================
// Block = 64 nodes (4 waves). Phase 1: one node per 16-lane quarter (16 lanes x
// 8 feats = 128); aggregate in registers with 8-deep load batching (doubles
// in-flight gathers vs 4-deep; gather is latency-bound per R3 counters),
// residual-mix, write MFMA A-frags into swizzled LDS. Phase 2: GEMM
// h_out = elu(s @ W'_l), A from LDS, B direct from global (L2-resident 64 KB).
template <int LAST>
__global__ __launch_bounds__(256, 4) void spmm_gemm(const int* __restrict__ row_ptr,
        const int2* __restrict__ rec, const float* __restrict__ dinv,
        const unsigned short* __restrict__ hin, const unsigned short* __restrict__ h0b,
        const unsigned short* __restrict__ wlp, void* __restrict__ outp) {
    __shared__ __align__(16) unsigned short afr[16384];   // 32 KB A-frags / out-tile union
    int tid = threadIdx.x;
    int wave = tid >> 6, lane = tid & 63;
    int qu = lane >> 4, fl = lane & 15;
    char* af = (char*)afr;

    // ---- phase 1: aggregation, 4 rounds of (node per quarter) ----
    int base = blockIdx.x * 64 + wave * 16;
#pragma unroll 1
    for (int g = 0; g < 4; ++g) {
        int node = base + g * 4 + qu;
        int nc = (node < N_NODES) ? node : (N_NODES - 1);
        int e0 = row_ptr[nc], e1 = row_ptr[nc + 1];
        // issue self/residual loads early (overlap with gather)
        float dd = dinv[nc];
        uint4 hv = *(const uint4*)(hin + (size_t)nc * HID + fl * 8);
        uint4 zv = *(const uint4*)(h0b + (size_t)nc * HID + fl * 8);
        float a[8] = {0.f, 0.f, 0.f, 0.f, 0.f, 0.f, 0.f, 0.f};
        int e = e0;
        for (; e + 7 < e1; e += 8) {
            int2 r0 = rec[e],     r1 = rec[e + 1], r2 = rec[e + 2], r3 = rec[e + 3];
            int2 r4 = rec[e + 4], r5 = rec[e + 5], r6 = rec[e + 6], r7 = rec[e + 7];
            uint4 u0 = *(const uint4*)(hin + (size_t)r0.x * HID + fl * 8);
            uint4 u1 = *(const uint4*)(hin + (size_t)r1.x * HID + fl * 8);
            uint4 u2 = *(const uint4*)(hin + (size_t)r2.x * HID + fl * 8);
            uint4 u3 = *(const uint4*)(hin + (size_t)r3.x * HID + fl * 8);
            uint4 u4 = *(const uint4*)(hin + (size_t)r4.x * HID + fl * 8);
            uint4 u5 = *(const uint4*)(hin + (size_t)r5.x * HID + fl * 8);
            uint4 u6 = *(const uint4*)(hin + (size_t)r6.x * HID + fl * 8);
            uint4 u7 = *(const uint4*)(hin + (size_t)r7.x * HID + fl * 8);
            bf8_fma(a, u0, __int_as_float(r0.y));
            bf8_fma(a, u1, __int_as_float(r1.y));
            bf8_fma(a, u2, __int_as_float(r2.y));
            bf8_fma(a, u3, __int_as_float(r3.y));
            bf8_fma(a, u4, __int_as_float(r4.y));
            bf8_fma(a, u5, __int_as_float(r5.y));
            bf8_fma(a, u6, __int_as_float(r6.y));
            bf8_fma(a, u7, __int_as_float(r7.y));
        }
        for (; e + 3 < e1; e += 4) {
            int2 r0 = rec[e], r1 = rec[e + 1], r2 = rec[e + 2], r3 = rec[e + 3];
            uint4 u0 = *(const uint4*)(hin + (size_t)r0.x * HID + fl * 8);
            uint4 u1 = *(const uint4*)(hin + (size_t)r1.x * HID + fl * 8);
            uint4 u2 = *(const uint4*)(hin + (size_t)r2.x * HID + fl * 8);
            uint4 u3 = *(const uint4*)(hin + (size_t)r3.x * HID + fl * 8);
            bf8_fma(a, u0, __int_as_float(r0.y));
            bf8_fma(a, u1, __int_as_float(r1.y));
            bf8_fma(a, u2, __int_as_float(r2.y));
            bf8_fma(a, u3, __int_as_float(r3.y));
        }
        for (; e < e1; ++e) {
            int2 r0 = rec[e];
            uint4 u0 = *(const uint4*)(hin + (size_t)r0.x * HID + fl * 8);
            bf8_fma(a, u0, __int_as_float(r0.y));
        }
        // self-loop + initial-residual mix
        float d2 = dd * dd;
        float hvf[8], zvf[8];
        unpack8(hvf, hv);
        unpack8(zvf, zv);
        short8 ohi, olo;
#pragma unroll
        for (int j = 0; j < 8; ++j) {
            float o = 0.9f * (a[j] + d2 * hvf[j]) + 0.1f * zvf[j];
            split_into(ohi, olo, j, o);
        }
        // A-frag layout: byte = wave*8192 + c*2048 + sel*1024 + q*256 + m*16
        // writer: c = fl>>2, q = fl&3, m = row within wave tile
        int mrow = g * 4 + qu;
        int b0 = wave * 8192 + (fl >> 2) * 2048 + (fl & 3) * 256 + mrow * 16;
        *(short8*)(af + SWZB(b0)) = ohi;
        *(short8*)(af + SWZB(b0 + 1024)) = olo;
    }
    __syncthreads();   // all A-frags visible

    // ---- phase 2: GEMM, A from LDS, B from global ----
    float4v acc[8];
#pragma unroll
    for (int nt = 0; nt < 8; ++nt) acc[nt] = (float4v){0.f, 0.f, 0.f, 0.f};
    const short8* wp8 = (const short8*)wlp;
#pragma unroll
    for (int c = 0; c < 4; ++c) {
        int rb = wave * 8192 + c * 2048 + lane * 16;
        short8 ahi = *(const short8*)(af + SWZB(rb));
        short8 alo = *(const short8*)(af + SWZB(rb + 1024));
#pragma unroll
        for (int nt = 0; nt < 8; ++nt) {
            short8 bhi = wp8[(size_t)(c * 8 + nt) * 128 + lane];
            short8 blo = wp8[(size_t)(c * 8 + nt) * 128 + 64 + lane];
            acc[nt] = __builtin_amdgcn_mfma_f32_16x16x32_bf16(ahi, bhi, acc[nt], 0, 0, 0);
            acc[nt] = __builtin_amdgcn_mfma_f32_16x16x32_bf16(ahi, blo, acc[nt], 0, 0, 0);
            acc[nt] = __builtin_amdgcn_mfma_f32_16x16x32_bf16(alo, bhi, acc[nt], 0, 0, 0);
        }
    }

    if (LAST) {
        // write f32 h for the out GEMM
        int t = blockIdx.x * 4 + wave;
        if (t < NT) {
            float* hf = (float*)outp;
#pragma unroll
            for (int nt = 0; nt < 8; ++nt) {
#pragma unroll
                for (int r = 0; r < 4; ++r) {
                    float v = acc[nt][r];
                    v = (v > 0.f) ? v : (expf(v) - 1.0f);
                    hf[(size_t)(t * 16 + qu * 4 + r) * HID + nt * 16 + fl] = v;
                }
            }
        }
    } else {
        __syncthreads();   // A-frag reads done; reuse afr as output tile
        unsigned short (*tile)[136] = (unsigned short (*)[136])afr;
#pragma unroll
        for (int nt = 0; nt < 8; ++nt) {
#pragma unroll
            for (int r = 0; r < 4; ++r) {
                float v = acc[nt][r];
                v = (v > 0.f) ? v : (expf(v) - 1.0f);
                tile[wave * 16 + qu * 4 + r][nt * 16 + fl] = f2bf(v);
            }
        }
        __syncthreads();
        unsigned short* hout = (unsigned short*)outp;
        int nl = tid >> 2, part = tid & 3;
        int node = blockIdx.x * 64 + nl;
        if (node < N_NODES) {
            uint4* d1 = (uint4*)&hout[(size_t)node * HID + part * 32];
#pragma unroll
            for (int j = 0; j < 4; ++j) d1[j] = *(uint4*)&tile[nl][part * 32 + j * 8];
        }
    }
}

// ================= out GEMM + log_softmax (split-bf16 MFMA) =================
__global__ __launch_bounds__(256) void out_gemm(const float* __restrict__ hf,
        const unsigned short* __restrict__ wop, const float* __restrict__ bias,
        float* __restrict__ out) {
    int wave = threadIdx.x >> 6;
    int lane = threadIdx.x & 63;
    int t = blockIdx.x * 4 + wave;
    int m = lane & 15, q = lane >> 4;
    if (t >= NT) return;

    float4v acc[4];
#pragma unroll
    for (int nt = 0; nt < 4; nt++) acc[nt] = (float4v){0.f, 0.f, 0.f, 0.f};
    const float* hr = hf + (size_t)(t * 16 + m) * HID + q * 8;
    const short8* wp8 = (const short8*)wop;
#pragma unroll
    for (int c = 0; c < 4; c++) {
        float4 x0 = *(const float4*)(hr + c * 32);
        float4 x1 = *(const float4*)(hr + c * 32 + 4);
        short8 ahi, alo;
        split_into(ahi, alo, 0, x0.x); split_into(ahi, alo, 1, x0.y);
        split_into(ahi, alo, 2, x0.z); split_into(ahi, alo, 3, x0.w);
        split_into(ahi, alo, 4, x1.x); split_into(ahi, alo, 5, x1.y);
        split_into(ahi, alo, 6, x1.z); split_into(ahi, alo, 7, x1.w);
#pragma unroll
        for (int nt = 0; nt < 4; nt++) {
            short8 bhi = wp8[(size_t)(nt * 4 + c) * 128 + lane];
            short8 blo = wp8[(size_t)(nt * 4 + c) * 128 + 64 + lane];
            acc[nt] = __builtin_amdgcn_mfma_f32_16x16x32_bf16(ahi, bhi, acc[nt], 0, 0, 0);
            acc[nt] = __builtin_amdgcn_mfma_f32_16x16x32_bf16(ahi, blo, acc[nt], 0, 0, 0);
            acc[nt] = __builtin_amdgcn_mfma_f32_16x16x32_bf16(alo, bhi, acc[nt], 0, 0, 0);
        }
    }
    float bn[4];
#pragma unroll
    for (int nt = 0; nt < 4; nt++) bn[nt] = bias[nt * 16 + m];
#pragma unroll
    for (int r = 0; r < 4; r++) {
        float v0 = acc[0][r] + bn[0], v1 = acc[1][r] + bn[1];
        float v2 = acc[2][r] + bn[2], v3 = acc[3][r] + bn[3];
        float mx = fmaxf(fmaxf(v0, v1), fmaxf(v2, v3));
#pragma unroll
        for (int msk = 1; msk < 16; msk <<= 1) mx = fmaxf(mx, __shfl_xor(mx, msk));
        float ssum = expf(v0 - mx) + expf(v1 - mx) + expf(v2 - mx) + expf(v3 - mx);
#pragma unroll
        for (int msk = 1; msk < 16; msk <<= 1) ssum += __shfl_xor(ssum, msk);
        float lg = mx + logf(ssum);
        size_t base = (size_t)(t * 16 + q * 4 + r) * NCLS + m;
        out[base]      = v0 - lg;
        out[base + 16] = v1 - lg;
        out[base + 32] = v2 - lg;
        out[base + 48] = v3 - lg;
    }
}

// ================= launch =================

extern "C" void kernel_launch(void* const* d_in, const int* in_sizes, int n_in,
                              void* d_out, int out_size, void* d_ws, size_t ws_size,
                              hipStream_t stream) {
    const float* x      = (const float*)d_in[0];
    const int*   ei     = (const int*)  d_in[1];
    const float* w_in   = (const float*)d_in[2];
    const float* b_in   = (const float*)d_in[3];
    const float* conv_w = (const float*)d_in[4];
    const float* w_out  = (const float*)d_in[5];
    const float* b_out  = (const float*)d_in[6];
    float* out = (float*)d_out;

    const int* srcI = ei;
    const int* dstI = ei + N_EDGES;

    char* ws = (char*)d_ws;
    float* dinv    = (float*)(ws + 0x000000);
    int*   cnt     = (int*)  (ws + 0x080000);
    int*   partial = (int*)  (ws + 0x100000);
    int*   bsum    = (int*)  (ws + 0x180000);
    int*   row_ptr = (int*)  (ws + 0x190000);
    int*   cursor  = (int*)  (ws + 0x200000);
    int2*  rec     = (int2*) (ws + 0x280000);                  // 12.8 MB
    unsigned short* wip = (unsigned short*)(ws + 0xF00000);    // 256 KB
    unsigned short* wlp = (unsigned short*)(ws + 0xF40000);    // 512 KB
    unsigned short* wop = (unsigned short*)(ws + 0xFC0000);    // 32 KB
    unsigned short* hb  = (unsigned short*)(ws + 0x1000000);   // 25.6 MB
    unsigned short* h0b = hb + (size_t)N_NODES * HID;          // 25.6 MB
    unsigned short* hb2 = h0b + (size_t)N_NODES * HID;         // 25.6 MB (ping-pong)
    float* hf = (float*)(hb2 + 2 * (size_t)N_NODES * HID);     // 51.2 MB

    int gN = (N_NODES + 255) / 256;
    int gE = (N_EDGES + 255) / 256;
    int gT = (NT + 3) / 4;                                     // 1563 (= 64-node blocks)

    cnt_init<<<gN, 256, 0, stream>>>(cnt);
    cnt_count<<<gE, 256, 0, stream>>>(dstI, cnt);
    make_dinv<<<gN, 256, 0, stream>>>(cnt, dinv);
    scan_block<<<NSCANB, 256, 0, stream>>>(cnt, partial, bsum);
    scan_bsum<<<1, 64, 0, stream>>>(bsum);
    finalize_rowptr<<<NSCANB, 256, 0, stream>>>(cnt, partial, bsum, row_ptr, cursor);
    scatter_edges<<<gE, 256, 0, stream>>>(srcI, dstI, dinv, cursor, rec);

    conv_win<<<128, 64, 0, stream>>>(w_in, wip);
    conv_wl<<<256, 64, 0, stream>>>(conv_w, wlp);
    conv_wout<<<16, 64, 0, stream>>>(w_out, wop);

    in_gemm_mfma<<<gT, 256, 0, stream>>>(x, wip, b_in, hb, h0b);

    unsigned short* cur = hb;
    unsigned short* nxt = hb2;
    for (int l = 0; l < NLAYERS; l++) {
        const unsigned short* wl = wlp + (size_t)l * 32768;
        if (l < NLAYERS - 1) {
            spmm_gemm<0><<<gT, 256, 0, stream>>>(row_ptr, rec, dinv, cur, h0b, wl, nxt);
            unsigned short* t = cur; cur = nxt; nxt = t;
        } else {
            spmm_gemm<1><<<gT, 256, 0, stream>>>(row_ptr, rec, dinv, cur, h0b, wl, hf);
        }
    }

    out_gemm<<<gT, 256, 0, stream>>>(hf, wop, b_out, out);
}